// Round 1
// baseline (555.416 us; speedup 1.0000x reference)
//
#include <hip/hip_runtime.h>
#include <math.h>

#define BB 4
#define TT 4096
#define HH 16
#define DD 64
#define GG 64
#define NRND 192
#define NBLK 63   // (TT-GG)/64
#define PAD 68

// One flash-style kernel, templated:
//   GLOB=false: block-sparse part. grid = BB*HH*NBLK. 64 queries/block, 5 key tiles
//               (own block, global block, 3 random-gather tiles).
//   GLOB=true : global part. grid = BB*HH*4. 16 queries/block, 64 contiguous key tiles.
// Thread layout (256 thr): rg = tid>>4 (row group, RI rows each), dg = tid&15.
//   QK: thread computes s[ri][jc] for j = dg + 16*jc  (lane-stride-1 K rows -> no LDS conflicts)
//   softmax row-reduce: __shfl_xor over the 16 contiguous dg-lanes (width 16)
//   PV: thread owns acc[ri][d0..d0+3], d0 = dg*4; P staged via LDS (broadcast reads)
template<bool GLOB>
__global__ __launch_bounds__(256, 2)
void bb_attn(const float* __restrict__ Q,
             const float* __restrict__ K,
             const float* __restrict__ V,
             const int* __restrict__ RIDX,
             float* __restrict__ OUT)
{
    constexpr int RI = GLOB ? 1 : 4;       // query rows per thread
    constexpr int QR = GLOB ? 16 : 64;     // query rows per block

    __shared__ __align__(16) float q_s[QR][PAD];
    __shared__ __align__(16) float k_s[64][PAD];
    __shared__ __align__(16) float v_s[64][PAD];
    __shared__ __align__(16) float p_s[QR][PAD];
    __shared__ int toks_s[NRND];

    const int tid = threadIdx.x;
    int bh, qtok0, n_tiles;
    if constexpr (GLOB) {
        bh     = blockIdx.x >> 2;
        qtok0  = (blockIdx.x & 3) * 16;
        n_tiles = TT / 64;
    } else {
        bh     = blockIdx.x & (BB * HH - 1);
        qtok0  = GG + (int)(blockIdx.x >> 6) * 64;
        n_tiles = 5;
        if (tid < NRND) toks_s[tid] = RIDX[tid];
    }
    const int b = bh >> 4;          // / HH
    const int h = bh & (HH - 1);

    // addr(t,d) = ((b*TT + t)*HH + h)*DD + d
    const size_t bh_off = ((size_t)b * TT * HH + h) * DD;

    // ---- load Q tile (rows qtok0 .. qtok0+QR-1) ----
    {
        const int row0 = tid >> 4, d4 = tid & 15;
        #pragma unroll
        for (int p = 0; p < QR / 16; ++p) {
            const int row = row0 + 16 * p;
            const float* src = Q + bh_off + (size_t)(qtok0 + row) * (HH * DD) + d4 * 4;
            *(float4*)&q_s[row][d4 * 4] = *(const float4*)src;
        }
    }

    const int rg = tid >> 4;
    const int dg = tid & 15;
    const int d0 = dg * 4;

    float acc[RI][4];
    float m_run[RI], l_run[RI];
    #pragma unroll
    for (int ri = 0; ri < RI; ++ri) {
        m_run[ri] = -INFINITY; l_run[ri] = 0.f;
        #pragma unroll
        for (int c = 0; c < 4; ++c) acc[ri][c] = 0.f;
    }

    for (int kt = 0; kt < n_tiles; ++kt) {
        __syncthreads();   // prev tile's PV reads (v_s,p_s) done before restage
        // ---- stage K/V tile (64 rows) ----
        {
            const int row0 = tid >> 4, d4 = tid & 15;
            bool contig; int base = 0;
            if constexpr (GLOB) { contig = true; base = kt * 64; }
            else { contig = (kt < 2); base = (kt == 0) ? qtok0 : 0; }
            if (contig) {
                #pragma unroll
                for (int p = 0; p < 4; ++p) {
                    const int row = row0 + 16 * p;
                    const size_t ga = bh_off + (size_t)(base + row) * (HH * DD) + d4 * 4;
                    *(float4*)&k_s[row][d4 * 4] = *(const float4*)(K + ga);
                    *(float4*)&v_s[row][d4 * 4] = *(const float4*)(V + ga);
                }
            } else {
                const int tb = (kt - 2) * 64;
                #pragma unroll
                for (int p = 0; p < 4; ++p) {
                    const int row = row0 + 16 * p;
                    const int tok = toks_s[tb + row];
                    const size_t ga = bh_off + (size_t)tok * (HH * DD) + d4 * 4;
                    *(float4*)&k_s[row][d4 * 4] = *(const float4*)(K + ga);
                    *(float4*)&v_s[row][d4 * 4] = *(const float4*)(V + ga);
                }
            }
        }
        __syncthreads();

        // ---- QK^T: s[ri][jc], j = dg + 16*jc ----
        float s[RI][4];
        #pragma unroll
        for (int ri = 0; ri < RI; ++ri)
            #pragma unroll
            for (int jc = 0; jc < 4; ++jc) s[ri][jc] = 0.f;

        #pragma unroll 4
        for (int d4 = 0; d4 < 16; ++d4) {
            float4 k4[4];
            #pragma unroll
            for (int jc = 0; jc < 4; ++jc)
                k4[jc] = *(const float4*)&k_s[dg + 16 * jc][d4 * 4];
            #pragma unroll
            for (int ri = 0; ri < RI; ++ri) {
                const float4 q4 = *(const float4*)&q_s[rg * RI + ri][d4 * 4];
                #pragma unroll
                for (int jc = 0; jc < 4; ++jc)
                    s[ri][jc] += q4.x * k4[jc].x + q4.y * k4[jc].y
                               + q4.z * k4[jc].z + q4.w * k4[jc].w;
            }
        }

        // ---- online softmax update ----
        #pragma unroll
        for (int ri = 0; ri < RI; ++ri) {
            float a0 = s[ri][0] * 0.125f, a1 = s[ri][1] * 0.125f;
            float a2 = s[ri][2] * 0.125f, a3 = s[ri][3] * 0.125f;
            float tm = fmaxf(fmaxf(a0, a1), fmaxf(a2, a3));
            #pragma unroll
            for (int off = 1; off < 16; off <<= 1)
                tm = fmaxf(tm, __shfl_xor(tm, off, 16));
            const float mn = fmaxf(m_run[ri], tm);
            const float sc = __expf(m_run[ri] - mn);
            const float p0 = __expf(a0 - mn), p1 = __expf(a1 - mn);
            const float p2 = __expf(a2 - mn), p3 = __expf(a3 - mn);
            float ls = (p0 + p1) + (p2 + p3);
            #pragma unroll
            for (int off = 1; off < 16; off <<= 1)
                ls += __shfl_xor(ls, off, 16);
            l_run[ri] = l_run[ri] * sc + ls;
            m_run[ri] = mn;
            #pragma unroll
            for (int c = 0; c < 4; ++c) acc[ri][c] *= sc;
            const int r = rg * RI + ri;
            p_s[r][dg]      = p0;
            p_s[r][dg + 16] = p1;
            p_s[r][dg + 32] = p2;
            p_s[r][dg + 48] = p3;
        }
        __syncthreads();   // p_s visible to all

        // ---- PV: acc[ri][c] += sum_j p[r][j] * V[j][d0+c] ----
        #pragma unroll 4
        for (int jch = 0; jch < 16; ++jch) {
            float4 pr[RI];
            #pragma unroll
            for (int ri = 0; ri < RI; ++ri)
                pr[ri] = *(const float4*)&p_s[rg * RI + ri][jch * 4];
            #pragma unroll
            for (int jc = 0; jc < 4; ++jc) {
                const float4 v4 = *(const float4*)&v_s[jch * 4 + jc][d0];
                #pragma unroll
                for (int ri = 0; ri < RI; ++ri) {
                    const float pw = reinterpret_cast<const float*>(&pr[ri])[jc];
                    acc[ri][0] += pw * v4.x;
                    acc[ri][1] += pw * v4.y;
                    acc[ri][2] += pw * v4.z;
                    acc[ri][3] += pw * v4.w;
                }
            }
        }
    }

    // ---- epilogue: normalize + store ----
    #pragma unroll
    for (int ri = 0; ri < RI; ++ri) {
        const float inv = 1.0f / l_run[ri];
        const int tok = qtok0 + rg * RI + ri;
        float4 o;
        o.x = acc[ri][0] * inv; o.y = acc[ri][1] * inv;
        o.z = acc[ri][2] * inv; o.w = acc[ri][3] * inv;
        *(float4*)(OUT + bh_off + (size_t)tok * (HH * DD) + d0) = o;
    }
}

extern "C" void kernel_launch(void* const* d_in, const int* in_sizes, int n_in,
                              void* d_out, int out_size, void* d_ws, size_t ws_size,
                              hipStream_t stream) {
    const float* Q    = (const float*)d_in[0];
    const float* K    = (const float*)d_in[1];
    const float* V    = (const float*)d_in[2];
    const int*   RIDX = (const int*)d_in[3];
    float* OUT = (float*)d_out;

    // block-sparse part: 4*16*63 = 4032 blocks
    hipLaunchKernelGGL((bb_attn<false>), dim3(BB * HH * NBLK), dim3(256), 0, stream,
                       Q, K, V, RIDX, OUT);
    // global part: 4*16*4 = 256 blocks (64 global queries split 4-way)
    hipLaunchKernelGGL((bb_attn<true>), dim3(BB * HH * 4), dim3(256), 0, stream,
                       Q, K, V, RIDX, OUT);
}

// Round 2
// 284.149 us; speedup vs baseline: 1.9547x; 1.9547x over previous
//
#include <hip/hip_runtime.h>
#include <math.h>
#include <stdint.h>

#define BB 4
#define TT 4096
#define HH 16
#define DD 64
#define GG 64
#define NRND 192
#define HD 1024          // HH*DD
#define NBH 64           // BB*HH

typedef __attribute__((ext_vector_type(8))) short short8;
typedef __attribute__((ext_vector_type(4))) short short4v;
typedef __attribute__((ext_vector_type(16))) float f32x16;

__device__ __forceinline__ short bf_trunc_s(float f) {
    uint32_t u = __builtin_bit_cast(uint32_t, f);
    return (short)(u >> 16);
}
__device__ __forceinline__ short bf_rne_s(float f) {
    uint32_t u = __builtin_bit_cast(uint32_t, f);
    u += 0x7fffu + ((u >> 16) & 1u);
    return (short)(u >> 16);
}
__device__ __forceinline__ float bf_back(short s) {
    uint32_t u = ((uint32_t)(uint16_t)s) << 16;
    return __builtin_bit_cast(float, u);
}
__device__ __forceinline__ short8 ld8(const short* p) {
    short4v a = *(const short4v*)p;        // ds_read_b64 (8B aligned: stride 68 shorts)
    short4v b = *(const short4v*)(p + 4);
    short8 r;
    r[0]=a[0]; r[1]=a[1]; r[2]=a[2]; r[3]=a[3];
    r[4]=b[0]; r[5]=b[1]; r[6]=b[2]; r[7]=b[3];
    return r;
}

#define KS_STRIDE 68   // shorts; 136B rows: b64-aligned, bank step 2 -> 2-way (free)
#define VT_STRIDE 66   // shorts; 132B rows: b32-aligned, bank step 1 -> conflict-free
#define OS_STRIDE 67   // floats; bank step 3 (coprime 32) -> conflict-free scatter

// Unified BigBird kernel. grid = 64 global blocks + 4032 sparse blocks.
// Per block: 64 queries, 4 waves arranged (wq = q-half, wk = key-half).
// S^T = K·Q^T via mfma_32x32x16_bf16 with Q/K hi-lo split (3 MFMAs) for accuracy;
// softmax mostly in-register; P exchanged to PV B-operand via shfl_xor(32);
// out^T accumulated per (wk) wave, merged + transposed through LDS at epilogue.
__global__ __launch_bounds__(256, 4)
void bb_mfma(const float* __restrict__ Q, const float* __restrict__ K,
             const float* __restrict__ V, const int* __restrict__ RIDX,
             float* __restrict__ OUT)
{
    __shared__ __align__(16) char smem[64*KS_STRIDE*4 + 64*VT_STRIDE*2];
    short (*k_sh)[KS_STRIDE] = (short(*)[KS_STRIDE])(smem);
    short (*k_sl)[KS_STRIDE] = (short(*)[KS_STRIDE])(smem + 64*KS_STRIDE*2);
    short (*vt_s)[VT_STRIDE] = (short(*)[VT_STRIDE])(smem + 64*KS_STRIDE*4);
    float (*osum)[OS_STRIDE] = (float(*)[OS_STRIDE])(smem);   // epilogue alias of k_sh/k_sl only
    __shared__ float sm_m[2][64];
    __shared__ float sm_l[2][64];
    __shared__ int toks_s[NRND];

    const int tid  = threadIdx.x;
    const int bid  = blockIdx.x;
    const int lane = tid & 63;
    const int wid  = tid >> 6;
    const int wq   = wid >> 1;      // q-half (0,1)
    const int wk   = wid & 1;       // key-half (0,1)
    const int lq   = lane & 31;
    const int lh   = lane >> 5;

    const bool is_glob = bid < NBH;
    int bh, qtok0, ntiles;
    if (is_glob) { bh = bid; qtok0 = 0; ntiles = TT/64; }
    else {
        const int sid = bid - NBH;
        bh = sid & (NBH-1);
        qtok0 = GG + (sid >> 6) * 64;
        ntiles = 5;
        if (tid < NRND) toks_s[tid] = RIDX[tid];
    }
    const int b  = bh >> 4;
    const int hd = bh & 15;
    const size_t bh_off = ((size_t)b * TT * HH + hd) * DD;

    // ---- Q fragments (hi/lo trunc-split), B-operand layout: col=lq, k=16*ks+8*lh+j ----
    short8 qfh[4], qfl[4];
    {
        const float* qp = Q + bh_off + (size_t)(qtok0 + wq*32 + lq) * HD;
        #pragma unroll
        for (int ks = 0; ks < 4; ++ks) {
            const int f0 = ks*16 + lh*8;
            float4 fa = *(const float4*)(qp + f0);
            float4 fb = *(const float4*)(qp + f0 + 4);
            float fv[8] = {fa.x,fa.y,fa.z,fa.w, fb.x,fb.y,fb.z,fb.w};
            #pragma unroll
            for (int j = 0; j < 8; ++j) {
                short hi = bf_trunc_s(fv[j]);
                qfh[ks][j] = hi;
                qfl[ks][j] = bf_trunc_s(fv[j] - bf_back(hi));
            }
        }
    }

    f32x16 acc0, acc1;              // out^T partials: d in [0,32) and [32,64), q = wq*32+lq
    #pragma unroll
    for (int r = 0; r < 16; ++r) { acc0[r] = 0.f; acc1[r] = 0.f; }
    float m_run = -INFINITY, l_run = 0.f;

    for (int kt = 0; kt < ntiles; ++kt) {
        __syncthreads();   // prev tile's LDS reads complete before restage

        // ---- stage K (hi/lo) : [tok][feat] ----
        {
            const int tok = tid >> 2;
            const int f0  = (tid & 3) * 16;
            int gtok;
            if (is_glob)      gtok = kt*64 + tok;
            else if (kt == 0) gtok = qtok0 + tok;
            else if (kt == 1) gtok = tok;
            else              gtok = toks_s[(kt-2)*64 + tok];
            const float* kp = K + bh_off + (size_t)gtok * HD + f0;
            #pragma unroll
            for (int i = 0; i < 16; i += 4) {
                float4 f4 = *(const float4*)(kp + i);
                float fv[4] = {f4.x, f4.y, f4.z, f4.w};
                short4v hv, lv;
                #pragma unroll
                for (int j = 0; j < 4; ++j) {
                    short hi = bf_trunc_s(fv[j]);
                    hv[j] = hi;
                    lv[j] = bf_trunc_s(fv[j] - bf_back(hi));
                }
                *(short4v*)&k_sh[tok][f0 + i] = hv;
                *(short4v*)&k_sl[tok][f0 + i] = lv;
            }
        }
        // ---- stage V transposed: vT[d][tok] (packed pair writes) ----
        {
            const int d  = tid & 63;
            const int tg = tid >> 6;
            #pragma unroll
            for (int p = 0; p < 16; p += 2) {
                const int tok = tg*16 + p;
                int g0, g1;
                if (is_glob)      { g0 = kt*64 + tok;   g1 = g0 + 1; }
                else if (kt == 0) { g0 = qtok0 + tok;   g1 = g0 + 1; }
                else if (kt == 1) { g0 = tok;           g1 = tok + 1; }
                else { g0 = toks_s[(kt-2)*64 + tok]; g1 = toks_s[(kt-2)*64 + tok + 1]; }
                const float v0 = V[bh_off + (size_t)g0 * HD + d];
                const float v1 = V[bh_off + (size_t)g1 * HD + d];
                const uint32_t pk = (uint32_t)(uint16_t)bf_rne_s(v0)
                                  | ((uint32_t)(uint16_t)bf_rne_s(v1) << 16);
                *(uint32_t*)&vt_s[d][tok] = pk;
            }
        }
        __syncthreads();

        // ---- QK: S^T tile [32 keys of wk][32 q of wq], K-dim=64 = 4 ksteps ----
        f32x16 sc;
        #pragma unroll
        for (int r = 0; r < 16; ++r) sc[r] = 0.f;
        {
            const int krow = wk*32 + lq;
            #pragma unroll
            for (int ks = 0; ks < 4; ++ks) {
                const int f0 = ks*16 + lh*8;
                const short8 akh = ld8(&k_sh[krow][f0]);
                const short8 akl = ld8(&k_sl[krow][f0]);
                sc = __builtin_amdgcn_mfma_f32_32x32x16_bf16(akh, qfh[ks], sc, 0, 0, 0);
                sc = __builtin_amdgcn_mfma_f32_32x32x16_bf16(akh, qfl[ks], sc, 0, 0, 0);
                sc = __builtin_amdgcn_mfma_f32_32x32x16_bf16(akl, qfh[ks], sc, 0, 0, 0);
            }
        }

        // ---- online softmax (scaled domain); m shared across wk via LDS ----
        float pm = sc[0];
        #pragma unroll
        for (int r = 1; r < 16; ++r) pm = fmaxf(pm, sc[r]);
        pm *= 0.125f;
        pm = fmaxf(pm, __shfl_xor(pm, 32));
        if (lane < 32) sm_m[wk][wq*32 + lq] = pm;
        __syncthreads();
        const float tmax = fmaxf(sm_m[0][wq*32 + lq], sm_m[1][wq*32 + lq]);
        const float mnew = fmaxf(m_run, tmax);
        const float cf   = __expf(m_run - mnew);
        float p[16];
        float ls = 0.f;
        #pragma unroll
        for (int r = 0; r < 16; ++r) {
            p[r] = __expf(sc[r]*0.125f - mnew);
            ls += p[r];
        }
        ls += __shfl_xor(ls, 32);
        l_run = l_run * cf + ls;
        m_run = mnew;
        #pragma unroll
        for (int r = 0; r < 16; ++r) { acc0[r] *= cf; acc1[r] *= cf; }

        // ---- PV: out^T += V^T · P^T ; P^T B-operand built via lane-half exchange ----
        #pragma unroll
        for (int s = 0; s < 2; ++s) {
            float sh[8];
            #pragma unroll
            for (int j = 0; j < 8; ++j) sh[j] = __shfl_xor(p[8*s + j], 32);
            short8 pf;
            #pragma unroll
            for (int j = 0; j < 8; ++j) {
                float val;
                if (lh == 0) val = (j < 4) ? p[8*s + j] : sh[j - 4];
                else         val = (j < 4) ? sh[4 + j] : p[8*s + j];
                pf[j] = bf_rne_s(val);
            }
            const int t0 = wk*32 + s*16 + lh*8;
            union { uint32_t u[4]; short8 v; } c0, c1;
            const uint32_t* vp0 = (const uint32_t*)&vt_s[lq     ][t0];
            const uint32_t* vp1 = (const uint32_t*)&vt_s[lq + 32][t0];
            c0.u[0]=vp0[0]; c0.u[1]=vp0[1]; c0.u[2]=vp0[2]; c0.u[3]=vp0[3];
            c1.u[0]=vp1[0]; c1.u[1]=vp1[1]; c1.u[2]=vp1[2]; c1.u[3]=vp1[3];
            acc0 = __builtin_amdgcn_mfma_f32_32x32x16_bf16(c0.v, pf, acc0, 0, 0, 0);
            acc1 = __builtin_amdgcn_mfma_f32_32x32x16_bf16(c1.v, pf, acc1, 0, 0, 0);
        }
    }

    // ---- epilogue: merge wk halves, normalize, transpose via LDS, store ----
    if (lane < 32) sm_l[wk][wq*32 + lq] = l_run;
    if (wk == 0) {
        #pragma unroll
        for (int r = 0; r < 16; ++r) {
            const int dr = (r & 3) + 8*(r >> 2) + 4*lh;
            osum[wq*32 + lq][dr     ] = acc0[r];
            osum[wq*32 + lq][dr + 32] = acc1[r];
        }
    }
    __syncthreads();
    if (wk == 1) {
        #pragma unroll
        for (int r = 0; r < 16; ++r) {
            const int dr = (r & 3) + 8*(r >> 2) + 4*lh;
            osum[wq*32 + lq][dr     ] += acc0[r];
            osum[wq*32 + lq][dr + 32] += acc1[r];
        }
    }
    __syncthreads();
    {
        const int q  = tid >> 2;
        const int d0 = (tid & 3) * 16;
        const float inv = 1.f / (sm_l[0][q] + sm_l[1][q]);
        float* dst = OUT + bh_off + (size_t)(qtok0 + q) * HD + d0;
        #pragma unroll
        for (int i = 0; i < 16; i += 4) {
            float4 o;
            o.x = osum[q][d0 + i    ] * inv;
            o.y = osum[q][d0 + i + 1] * inv;
            o.z = osum[q][d0 + i + 2] * inv;
            o.w = osum[q][d0 + i + 3] * inv;
            *(float4*)(dst + i) = o;
        }
    }
}

extern "C" void kernel_launch(void* const* d_in, const int* in_sizes, int n_in,
                              void* d_out, int out_size, void* d_ws, size_t ws_size,
                              hipStream_t stream) {
    const float* Q    = (const float*)d_in[0];
    const float* K    = (const float*)d_in[1];
    const float* V    = (const float*)d_in[2];
    const int*   RIDX = (const int*)d_in[3];
    float* OUT = (float*)d_out;

    // 64 global blocks first (long: 64 tiles each), then 4032 sparse blocks (5 tiles each)
    hipLaunchKernelGGL(bb_mfma, dim3(NBH + BB*HH*63), dim3(256), 0, stream,
                       Q, K, V, RIDX, OUT);
}

// Round 3
// 166.249 us; speedup vs baseline: 3.3409x; 1.7092x over previous
//
#include <hip/hip_runtime.h>
#include <math.h>
#include <stdint.h>

#define BB 4
#define TT 4096
#define HH 16
#define DD 64
#define GG 64
#define NRND 192
#define HD 1024          // HH*DD
#define NBH 64           // BB*HH
#define NCHUNK 8         // key-chunks for the global part (8 tiles each)
#define NGBLK (NBH*NCHUNK)   // 512 global-chunk blocks
#define NSPB  (NBH*63)       // 4032 sparse blocks

typedef __attribute__((ext_vector_type(8))) short short8;
typedef __attribute__((ext_vector_type(4))) short short4v;
typedef __attribute__((ext_vector_type(16))) float f32x16;

__device__ __forceinline__ short bf_trunc_s(float f) {
    uint32_t u = __builtin_bit_cast(uint32_t, f);
    return (short)(u >> 16);
}
__device__ __forceinline__ short bf_rne_s(float f) {
    uint32_t u = __builtin_bit_cast(uint32_t, f);
    u += 0x7fffu + ((u >> 16) & 1u);
    return (short)(u >> 16);
}
__device__ __forceinline__ float bf_back(short s) {
    uint32_t u = ((uint32_t)(uint16_t)s) << 16;
    return __builtin_bit_cast(float, u);
}
__device__ __forceinline__ short8 ld8(const short* p) {
    short4v a = *(const short4v*)p;        // ds_read_b64 (8B aligned: stride 68 shorts)
    short4v b = *(const short4v*)(p + 4);
    short8 r;
    r[0]=a[0]; r[1]=a[1]; r[2]=a[2]; r[3]=a[3];
    r[4]=b[0]; r[5]=b[1]; r[6]=b[2]; r[7]=b[3];
    return r;
}

#define KS_STRIDE 68   // shorts; 136B rows: b64-aligned, bank step 2 -> 2-way (free)
#define VT_STRIDE 66   // shorts; 132B rows: b32-aligned, bank step 1 -> conflict-free
#define OS_STRIDE 67   // floats; bank step 3 (coprime 32) -> conflict-free scatter

// Unified BigBird kernel.
// grid = 512 global-chunk blocks (8 key-tiles each, flash partials -> ws)
//      + 4032 sparse blocks (5 key-tiles each, final -> OUT).
// Per block: 64 queries, 4 waves (wq = q-half, wk = key-half).
// S^T = K·Q^T via mfma_32x32x16_bf16 with Q/K hi-lo split (3 MFMAs) for accuracy.
// Each wk-half keeps independent (m,l,acc); halves merged in the epilogue with
// exp(m_i - M) scaling -> no per-tile cross-wave exchange, 2 barriers/tile.
__global__ __launch_bounds__(256, 4)
void bb_mfma(const float* __restrict__ Q, const float* __restrict__ K,
             const float* __restrict__ V, const int* __restrict__ RIDX,
             float* __restrict__ OUT, float* __restrict__ WS)
{
    __shared__ __align__(16) char smem[64*KS_STRIDE*4 + 64*VT_STRIDE*2];
    short (*k_sh)[KS_STRIDE] = (short(*)[KS_STRIDE])(smem);
    short (*k_sl)[KS_STRIDE] = (short(*)[KS_STRIDE])(smem + 64*KS_STRIDE*2);
    short (*vt_s)[VT_STRIDE] = (short(*)[VT_STRIDE])(smem + 64*KS_STRIDE*4);
    float (*osum)[OS_STRIDE] = (float(*)[OS_STRIDE])(smem);   // epilogue alias of k_sh/k_sl only
    __shared__ float sm_m[2][64];
    __shared__ float sm_l[2][64];
    __shared__ int toks_s[NRND];

    const int tid  = threadIdx.x;
    const int bid  = blockIdx.x;
    const int lane = tid & 63;
    const int wid  = tid >> 6;
    const int wq   = wid >> 1;      // q-half (0,1)
    const int wk   = wid & 1;       // key-half (0,1)
    const int lq   = lane & 31;
    const int lh   = lane >> 5;

    const bool is_glob = bid < NGBLK;
    int bh, qtok0, ntiles, kt0 = 0, chunk = 0;
    if (is_glob) {
        bh     = bid >> 3;
        chunk  = bid & (NCHUNK - 1);
        kt0    = chunk * 8;
        qtok0  = 0;
        ntiles = 8;
    } else {
        const int sid = bid - NGBLK;
        bh = sid & (NBH-1);
        qtok0 = GG + (sid >> 6) * 64;
        ntiles = 5;
        if (tid < NRND) toks_s[tid] = RIDX[tid];
    }
    const int b  = bh >> 4;
    const int hd = bh & 15;
    const size_t bh_off = ((size_t)b * TT * HH + hd) * DD;

    // ---- Q fragments (hi/lo trunc-split), B-operand layout: col=lq, k=16*ks+8*lh+j ----
    short8 qfh[4], qfl[4];
    {
        const float* qp = Q + bh_off + (size_t)(qtok0 + wq*32 + lq) * HD;
        #pragma unroll
        for (int ks = 0; ks < 4; ++ks) {
            const int f0 = ks*16 + lh*8;
            float4 fa = *(const float4*)(qp + f0);
            float4 fb = *(const float4*)(qp + f0 + 4);
            float fv[8] = {fa.x,fa.y,fa.z,fa.w, fb.x,fb.y,fb.z,fb.w};
            #pragma unroll
            for (int j = 0; j < 8; ++j) {
                short hi = bf_trunc_s(fv[j]);
                qfh[ks][j] = hi;
                qfl[ks][j] = bf_trunc_s(fv[j] - bf_back(hi));
            }
        }
    }

    f32x16 acc0, acc1;              // out^T partials: d in [0,32) and [32,64), q = wq*32+lq
    #pragma unroll
    for (int r = 0; r < 16; ++r) { acc0[r] = 0.f; acc1[r] = 0.f; }
    float m_run = -INFINITY, l_run = 0.f;

    for (int kt = 0; kt < ntiles; ++kt) {
        __syncthreads();   // prev tile's LDS reads complete before restage

        // ---- stage K (hi/lo) : [tok][feat] ----
        {
            const int tok = tid >> 2;
            const int f0  = (tid & 3) * 16;
            int gtok;
            if (is_glob)      gtok = (kt0 + kt)*64 + tok;
            else if (kt == 0) gtok = qtok0 + tok;
            else if (kt == 1) gtok = tok;
            else              gtok = toks_s[(kt-2)*64 + tok];
            const float* kp = K + bh_off + (size_t)gtok * HD + f0;
            #pragma unroll
            for (int i = 0; i < 16; i += 4) {
                float4 f4 = *(const float4*)(kp + i);
                float fv[4] = {f4.x, f4.y, f4.z, f4.w};
                short4v hv, lv;
                #pragma unroll
                for (int j = 0; j < 4; ++j) {
                    short hi = bf_trunc_s(fv[j]);
                    hv[j] = hi;
                    lv[j] = bf_trunc_s(fv[j] - bf_back(hi));
                }
                *(short4v*)&k_sh[tok][f0 + i] = hv;
                *(short4v*)&k_sl[tok][f0 + i] = lv;
            }
        }
        // ---- stage V transposed: vT[d][tok] (packed pair writes) ----
        {
            const int d  = tid & 63;
            const int tg = tid >> 6;
            #pragma unroll
            for (int p = 0; p < 16; p += 2) {
                const int tok = tg*16 + p;
                int g0, g1;
                if (is_glob)      { g0 = (kt0 + kt)*64 + tok; g1 = g0 + 1; }
                else if (kt == 0) { g0 = qtok0 + tok;   g1 = g0 + 1; }
                else if (kt == 1) { g0 = tok;           g1 = tok + 1; }
                else { g0 = toks_s[(kt-2)*64 + tok]; g1 = toks_s[(kt-2)*64 + tok + 1]; }
                const float v0 = V[bh_off + (size_t)g0 * HD + d];
                const float v1 = V[bh_off + (size_t)g1 * HD + d];
                const uint32_t pk = (uint32_t)(uint16_t)bf_rne_s(v0)
                                  | ((uint32_t)(uint16_t)bf_rne_s(v1) << 16);
                *(uint32_t*)&vt_s[d][tok] = pk;
            }
        }
        __syncthreads();

        // ---- QK: S^T tile [32 keys of wk][32 q of wq], K-dim=64 = 4 ksteps ----
        f32x16 sc;
        #pragma unroll
        for (int r = 0; r < 16; ++r) sc[r] = 0.f;
        {
            const int krow = wk*32 + lq;
            #pragma unroll
            for (int ks = 0; ks < 4; ++ks) {
                const int f0 = ks*16 + lh*8;
                const short8 akh = ld8(&k_sh[krow][f0]);
                const short8 akl = ld8(&k_sl[krow][f0]);
                sc = __builtin_amdgcn_mfma_f32_32x32x16_bf16(akh, qfh[ks], sc, 0, 0, 0);
                sc = __builtin_amdgcn_mfma_f32_32x32x16_bf16(akh, qfl[ks], sc, 0, 0, 0);
                sc = __builtin_amdgcn_mfma_f32_32x32x16_bf16(akl, qfh[ks], sc, 0, 0, 0);
            }
        }

        // ---- online softmax, fully in-wave (wk-halves independent) ----
        float pm = sc[0];
        #pragma unroll
        for (int r = 1; r < 16; ++r) pm = fmaxf(pm, sc[r]);
        pm *= 0.125f;
        pm = fmaxf(pm, __shfl_xor(pm, 32));     // combine 16-key halves within wave
        const float mnew = fmaxf(m_run, pm);
        const float cf   = __expf(m_run - mnew);
        float p[16];
        float ls = 0.f;
        #pragma unroll
        for (int r = 0; r < 16; ++r) {
            p[r] = __expf(sc[r]*0.125f - mnew);
            ls += p[r];
        }
        ls += __shfl_xor(ls, 32);
        l_run = l_run * cf + ls;
        m_run = mnew;
        #pragma unroll
        for (int r = 0; r < 16; ++r) { acc0[r] *= cf; acc1[r] *= cf; }

        // ---- PV: out^T += V^T · P^T ; P^T B-operand built via lane-half exchange ----
        #pragma unroll
        for (int s = 0; s < 2; ++s) {
            float sh[8];
            #pragma unroll
            for (int j = 0; j < 8; ++j) sh[j] = __shfl_xor(p[8*s + j], 32);
            short8 pf;
            #pragma unroll
            for (int j = 0; j < 8; ++j) {
                float val;
                if (lh == 0) val = (j < 4) ? p[8*s + j] : sh[j - 4];
                else         val = (j < 4) ? sh[4 + j] : p[8*s + j];
                pf[j] = bf_rne_s(val);
            }
            const int t0 = wk*32 + s*16 + lh*8;
            union { uint32_t u[4]; short8 v; } c0, c1;
            const uint32_t* vp0 = (const uint32_t*)&vt_s[lq     ][t0];
            const uint32_t* vp1 = (const uint32_t*)&vt_s[lq + 32][t0];
            c0.u[0]=vp0[0]; c0.u[1]=vp0[1]; c0.u[2]=vp0[2]; c0.u[3]=vp0[3];
            c1.u[0]=vp1[0]; c1.u[1]=vp1[1]; c1.u[2]=vp1[2]; c1.u[3]=vp1[3];
            acc0 = __builtin_amdgcn_mfma_f32_32x32x16_bf16(c0.v, pf, acc0, 0, 0, 0);
            acc1 = __builtin_amdgcn_mfma_f32_32x32x16_bf16(c1.v, pf, acc1, 0, 0, 0);
        }
    }

    // ---- epilogue: merge wk halves (independent m), transpose via LDS ----
    if (lane < 32) { sm_m[wk][wq*32 + lq] = m_run; sm_l[wk][wq*32 + lq] = l_run; }
    __syncthreads();
    const int qrow = wq*32 + lq;
    const float Mq   = fmaxf(sm_m[0][qrow], sm_m[1][qrow]);
    const float wsc  = __expf(m_run - Mq);     // this wave's rescale to common max
    if (wk == 0) {
        #pragma unroll
        for (int r = 0; r < 16; ++r) {
            const int dr = (r & 3) + 8*(r >> 2) + 4*lh;
            osum[qrow][dr     ] = acc0[r] * wsc;
            osum[qrow][dr + 32] = acc1[r] * wsc;
        }
    }
    __syncthreads();
    if (wk == 1) {
        #pragma unroll
        for (int r = 0; r < 16; ++r) {
            const int dr = (r & 3) + 8*(r >> 2) + 4*lh;
            osum[qrow][dr     ] += acc0[r] * wsc;
            osum[qrow][dr + 32] += acc1[r] * wsc;
        }
    }
    __syncthreads();
    {
        const int q  = tid >> 2;
        const int d0 = (tid & 3) * 16;
        const float M     = fmaxf(sm_m[0][q], sm_m[1][q]);
        const float lcomb = __expf(sm_m[0][q] - M) * sm_l[0][q]
                          + __expf(sm_m[1][q] - M) * sm_l[1][q];
        if (is_glob) {
            // flash partials to workspace (unnormalized)
            float* WACC = WS;
            float* WM   = WS + (size_t)NGBLK * 4096;
            float* WL   = WM + (size_t)NGBLK * 64;
            const int slot = chunk * NBH + bh;
            float* dst = WACC + (size_t)slot * 4096 + q * 64 + d0;
            #pragma unroll
            for (int i = 0; i < 16; i += 4) {
                float4 o;
                o.x = osum[q][d0 + i    ];
                o.y = osum[q][d0 + i + 1];
                o.z = osum[q][d0 + i + 2];
                o.w = osum[q][d0 + i + 3];
                *(float4*)(dst + i) = o;
            }
            if ((tid & 3) == 0) {
                WM[slot * 64 + q] = M;
                WL[slot * 64 + q] = lcomb;
            }
        } else {
            const float inv = 1.f / lcomb;
            float* dst = OUT + bh_off + (size_t)(qtok0 + q) * HD + d0;
            #pragma unroll
            for (int i = 0; i < 16; i += 4) {
                float4 o;
                o.x = osum[q][d0 + i    ] * inv;
                o.y = osum[q][d0 + i + 1] * inv;
                o.z = osum[q][d0 + i + 2] * inv;
                o.w = osum[q][d0 + i + 3] * inv;
                *(float4*)(dst + i) = o;
            }
        }
    }
}

// Combine the NCHUNK flash partials for the 64 global query rows of each (b,h).
__global__ __launch_bounds__(256, 4)
void bb_combine(const float* __restrict__ WS, float* __restrict__ OUT)
{
    const int bh = blockIdx.x;
    const int b  = bh >> 4;
    const int hd = bh & 15;
    const size_t bh_off = ((size_t)b * TT * HH + hd) * DD;

    const float* WACC = WS;
    const float* WM   = WS + (size_t)NGBLK * 4096;
    const float* WL   = WM + (size_t)NGBLK * 64;

    const int q  = threadIdx.x >> 2;
    const int d0 = (threadIdx.x & 3) * 16;

    float m[NCHUNK];
    float M = -INFINITY;
    #pragma unroll
    for (int c = 0; c < NCHUNK; ++c) {
        m[c] = WM[(c * NBH + bh) * 64 + q];
        M = fmaxf(M, m[c]);
    }
    float w[NCHUNK];
    float denom = 0.f;
    #pragma unroll
    for (int c = 0; c < NCHUNK; ++c) {
        w[c] = __expf(m[c] - M);
        denom += w[c] * WL[(c * NBH + bh) * 64 + q];
    }
    const float inv = 1.f / denom;

    float* dst = OUT + bh_off + (size_t)q * HD + d0;
    #pragma unroll
    for (int i = 0; i < 16; i += 4) {
        float ox = 0.f, oy = 0.f, oz = 0.f, ow = 0.f;
        #pragma unroll
        for (int c = 0; c < NCHUNK; ++c) {
            const float4 a = *(const float4*)&WACC[(size_t)(c * NBH + bh) * 4096 + q * 64 + d0 + i];
            ox += w[c] * a.x; oy += w[c] * a.y;
            oz += w[c] * a.z; ow += w[c] * a.w;
        }
        float4 o; o.x = ox * inv; o.y = oy * inv; o.z = oz * inv; o.w = ow * inv;
        *(float4*)(dst + i) = o;
    }
}

extern "C" void kernel_launch(void* const* d_in, const int* in_sizes, int n_in,
                              void* d_out, int out_size, void* d_ws, size_t ws_size,
                              hipStream_t stream) {
    const float* Q    = (const float*)d_in[0];
    const float* K    = (const float*)d_in[1];
    const float* V    = (const float*)d_in[2];
    const int*   RIDX = (const int*)d_in[3];
    float* OUT = (float*)d_out;
    float* WS  = (float*)d_ws;

    // 512 balanced global-chunk blocks + 4032 sparse blocks
    hipLaunchKernelGGL(bb_mfma, dim3(NGBLK + NSPB), dim3(256), 0, stream,
                       Q, K, V, RIDX, OUT, WS);
    // combine global partials (writes OUT rows [0,64) per (b,h))
    hipLaunchKernelGGL(bb_combine, dim3(NBH), dim3(256), 0, stream, WS, OUT);
}

// Round 4
// 137.121 us; speedup vs baseline: 4.0506x; 1.2124x over previous
//
#include <hip/hip_runtime.h>
#include <math.h>
#include <stdint.h>

#define BB 4
#define TT 4096
#define HH 16
#define DD 64
#define GG 64
#define NRND 192
#define HD 1024          // HH*DD
#define NBH 64           // BB*HH
#define NCHUNK 8         // key-chunks for the global part (8 tiles each)
#define NGBLK (NBH*NCHUNK)   // 512 global-chunk blocks
#define NSPB  (NBH*63)       // 4032 sparse blocks

// ---- workspace layout (bytes); total ~77.3 MB ----
#define OFF_KBF  0u          // bf16 K, [bh][t][64]   row = 128 B
#define OFF_VT   33554432u   // bf16 V^T, [bh][d][TT]  row = 8192 B
#define OFF_VRT  67108864u   // bf16 V^T gathered random, [bh][d][192] row = 384 B
#define OFF_WACC 68681728u   // fp32 partials [512][4096]
#define OFF_WM   77070336u   // fp32 [512][64]
#define OFF_WL   77201408u   // fp32 [512][64]

typedef __attribute__((ext_vector_type(8))) short short8;
typedef __attribute__((ext_vector_type(16))) float f32x16;

__device__ __forceinline__ ushort rne_u(float f) {
    uint32_t u = __builtin_bit_cast(uint32_t, f);
    u += 0x7fffu + ((u >> 16) & 1u);
    return (ushort)(u >> 16);
}
__device__ __forceinline__ short bf_trunc_s(float f) {
    uint32_t u = __builtin_bit_cast(uint32_t, f);
    return (short)(u >> 16);
}
__device__ __forceinline__ float bf_back(short s) {
    uint32_t u = ((uint32_t)(uint16_t)s) << 16;
    return __builtin_bit_cast(float, u);
}

// async global->LDS, 16B per lane; LDS dest = wave-uniform base + lane*16
typedef const __attribute__((address_space(1))) uint32_t* gas1_t;
typedef __attribute__((address_space(3))) uint32_t* las3_t;
__device__ __forceinline__ void gld16(const void* g, void* l) {
    __builtin_amdgcn_global_load_lds((gas1_t)g, (las3_t)l, 16, 0, 0);
}

#define MEMFENCE asm volatile("" ::: "memory")

// ============================================================================
// Prep: Kbf (bf16 rows), Vt (bf16 V^T per bh), Vrt (gathered random V^T)
// grid = 8192 (K convert) + 1024 (Vt transpose) + 64 (Vrt gather)
// ============================================================================
__global__ __launch_bounds__(256, 4)
void bb_prep(const float* __restrict__ K, const float* __restrict__ V,
             const int* __restrict__ RIDX, char* __restrict__ ws)
{
    __shared__ ushort vt_l[64][258];
    __shared__ int toks_c[NRND];
    const int bid = blockIdx.x, tid = threadIdx.x;

    if (bid < 8192) {
        // ---- K fp32 -> bf16, [b][t][h][d] -> [bh][t][d] ----
        const size_t gid = (size_t)bid * 256 + tid;
        const size_t r = gid >> 3;              // (b,t,h) row, 262144 rows
        const int d0 = (int)(gid & 7) * 8;
        const float* src = K + r * 64 + d0;
        const float4 f0 = *(const float4*)src;
        const float4 f1 = *(const float4*)(src + 4);
        const int h = (int)(r & 15);
        const int t = (int)((r >> 4) & 4095);
        const int b = (int)(r >> 16);
        short8 o;
        o[0]=(short)rne_u(f0.x); o[1]=(short)rne_u(f0.y);
        o[2]=(short)rne_u(f0.z); o[3]=(short)rne_u(f0.w);
        o[4]=(short)rne_u(f1.x); o[5]=(short)rne_u(f1.y);
        o[6]=(short)rne_u(f1.z); o[7]=(short)rne_u(f1.w);
        ushort* dst = (ushort*)(ws + OFF_KBF) + (((size_t)(b*16 + h) * TT + t) * 64 + d0);
        *(short8*)dst = o;
    } else if (bid < 8192 + 1024) {
        // ---- Vt: transpose one 256-token chunk of one (b,h) ----
        const int id = bid - 8192;
        const int bh = id >> 4, tc = id & 15;
        const int b = bh >> 4, h = bh & 15;
        #pragma unroll
        for (int ch = 0; ch < 4; ++ch) {
            const int tl = ch * 64 + (tid >> 2);        // local token 0..255
            const int tok = tc * 256 + tl;
            const int d0 = (tid & 3) * 16;
            const float* src = V + ((size_t)(b * TT + tok) * HH + h) * DD + d0;
            #pragma unroll
            for (int i = 0; i < 16; i += 4) {
                const float4 f = *(const float4*)(src + i);
                vt_l[d0 + i    ][tl] = rne_u(f.x);
                vt_l[d0 + i + 1][tl] = rne_u(f.y);
                vt_l[d0 + i + 2][tl] = rne_u(f.z);
                vt_l[d0 + i + 3][tl] = rne_u(f.w);
            }
        }
        __syncthreads();
        const int d = tid >> 2, seg = tid & 3;
        #pragma unroll
        for (int j8 = 0; j8 < 8; ++j8) {
            const int bt = seg * 64 + j8 * 8;
            short8 o;
            #pragma unroll
            for (int e = 0; e < 8; ++e) o[e] = (short)vt_l[d][bt + e];
            char* dst = ws + OFF_VT + (size_t)bh * 524288 + (size_t)d * 8192 + (tc * 256 + bt) * 2;
            *(short8*)dst = o;
        }
    } else {
        // ---- Vrt: gather random tokens, transposed ----
        const int bh = bid - 9216;
        const int b = bh >> 4, h = bh & 15;
        if (tid < NRND) toks_c[tid] = RIDX[tid];
        __syncthreads();
        #pragma unroll
        for (int ch = 0; ch < 3; ++ch) {
            const int slot = ch * 64 + (tid >> 2);      // 0..191
            const int tok = toks_c[slot];
            const int d0 = (tid & 3) * 16;
            const float* src = V + ((size_t)(b * TT + tok) * HH + h) * DD + d0;
            #pragma unroll
            for (int i = 0; i < 16; i += 4) {
                const float4 f = *(const float4*)(src + i);
                vt_l[d0 + i    ][slot] = rne_u(f.x);
                vt_l[d0 + i + 1][slot] = rne_u(f.y);
                vt_l[d0 + i + 2][slot] = rne_u(f.z);
                vt_l[d0 + i + 3][slot] = rne_u(f.w);
            }
        }
        __syncthreads();
        const int d = tid >> 2, seg = tid & 3;          // seg covers 48 slots
        #pragma unroll
        for (int j = 0; j < 6; ++j) {
            const int s0 = seg * 48 + j * 8;
            short8 o;
            #pragma unroll
            for (int e = 0; e < 8; ++e) o[e] = (short)vt_l[d][s0 + e];
            char* dst = ws + OFF_VRT + (size_t)bh * 24576 + (size_t)d * 384 + s0 * 2;
            *(short8*)dst = o;
        }
    }
}

// ============================================================================
// Main: flash attention over bf16 tiles staged via global_load_lds (dbuf).
// grid = 512 global-chunk blocks (8 tiles -> WS partials) + 4032 sparse blocks.
// LDS tiles linear [row][128B]; source chunk pre-swizzled c^(row&7), reads XOR.
// ============================================================================
__global__ __launch_bounds__(256, 4)
void bb_mfma(const float* __restrict__ Q, const int* __restrict__ RIDX,
             float* __restrict__ OUT, char* __restrict__ ws)
{
    __shared__ __align__(16) char smem[32768];   // [K buf0|K buf1|V buf0|V buf1], 8KB each
    __shared__ float sm_m[2][64];
    __shared__ float sm_l[2][64];
    __shared__ int toks_s[NRND];
    float (*osum)[67] = (float(*)[67])smem;      // epilogue alias

    const int tid  = threadIdx.x;
    const int bid  = blockIdx.x;
    const int lane = tid & 63;
    const int wid  = tid >> 6;
    const int wq   = wid >> 1;      // q-half
    const int wk   = wid & 1;       // key-half
    const int lq   = lane & 31;
    const int lh   = lane >> 5;

    const bool is_glob = bid < NGBLK;
    int bh, qtok0, ntiles, kt0 = 0, chunk = 0;
    if (is_glob) {
        bh = bid >> 3; chunk = bid & 7; kt0 = chunk * 8;
        qtok0 = 0; ntiles = 8;
    } else {
        const int sid = bid - NGBLK;
        bh = sid & (NBH - 1);
        qtok0 = GG + (sid >> 6) * 64;
        ntiles = 5;
    }
    const int b  = bh >> 4;
    const int hd = bh & 15;
    const size_t bh_off = ((size_t)b * TT * HH + hd) * DD;

    const char* kbf_bh = ws + OFF_KBF + (size_t)bh * 524288;
    const char* vt_bh  = ws + OFF_VT  + (size_t)bh * 524288;
    const char* vrt_bh = ws + OFF_VRT + (size_t)bh * 24576;

    // ---- Q raw loads first (keeps stage(0) loads uncounted in Q's waitcnt) ----
    float4 qa[4], qb[4];
    {
        const float* qp = Q + bh_off + (size_t)(qtok0 + wq*32 + lq) * HD;
        #pragma unroll
        for (int ks = 0; ks < 4; ++ks) {
            qa[ks] = *(const float4*)(qp + ks*16 + lh*8);
            qb[ks] = *(const float4*)(qp + ks*16 + lh*8 + 4);
        }
    }
    if (!is_glob && tid < NRND) toks_s[tid] = RIDX[tid];

    // ---- tile stager: 2 K-instrs + 2 V-instrs per wave ----
    auto stage_tile = [&](int buf, int kt_t) {
        const int rbase = wid * 16;
        #pragma unroll
        for (int i = 0; i < 2; ++i) {
            const int r0 = rbase + i*8;
            const int r  = r0 + (lane >> 3);
            const int cs = ((lane & 7) ^ (r & 7)) << 4;
            const char* ksrc;
            if (is_glob)           ksrc = kbf_bh + (size_t)((kt0 + kt_t)*64 + r)*128 + cs;
            else if (kt_t == 0)    ksrc = kbf_bh + (size_t)(qtok0 + r)*128 + cs;
            else if (kt_t == 1)    ksrc = kbf_bh + (size_t)r*128 + cs;
            else {
                const int tok = toks_s[(kt_t - 2)*64 + r];
                ksrc = kbf_bh + (size_t)tok*128 + cs;
            }
            gld16(ksrc, smem + buf*8192 + r0*128);
        }
        #pragma unroll
        for (int i = 0; i < 2; ++i) {
            const int r0 = rbase + i*8;
            const int d  = r0 + (lane >> 3);
            const int cs = ((lane & 7) ^ (d & 7)) << 4;
            const char* vsrc;
            if (is_glob)           vsrc = vt_bh + (size_t)d*8192 + (kt0 + kt_t)*128 + cs;
            else if (kt_t == 0)    vsrc = vt_bh + (size_t)d*8192 + qtok0*2 + cs;
            else if (kt_t == 1)    vsrc = vt_bh + (size_t)d*8192 + cs;
            else                   vsrc = vrt_bh + (size_t)d*384 + (kt_t - 2)*128 + cs;
            gld16(vsrc, smem + 16384 + buf*8192 + r0*128);
        }
    };

    stage_tile(0, 0);

    // ---- Q fragments (hi/lo trunc-split), B-operand: col=lq, k=16*ks+8*lh+j ----
    short8 qfh[4], qfl[4];
    #pragma unroll
    for (int ks = 0; ks < 4; ++ks) {
        float fv[8] = {qa[ks].x, qa[ks].y, qa[ks].z, qa[ks].w,
                       qb[ks].x, qb[ks].y, qb[ks].z, qb[ks].w};
        #pragma unroll
        for (int j = 0; j < 8; ++j) {
            const short hi = bf_trunc_s(fv[j]);
            qfh[ks][j] = hi;
            qfl[ks][j] = bf_trunc_s(fv[j] - bf_back(hi));
        }
    }

    f32x16 acc0, acc1;
    #pragma unroll
    for (int r = 0; r < 16; ++r) { acc0[r] = 0.f; acc1[r] = 0.f; }
    float m_run = -INFINITY, l_run = 0.f;

    for (int kt = 0; kt < ntiles; ++kt) {
        const int cur = kt & 1;
        const bool have_next = (kt + 1 < ntiles);
        if (have_next) stage_tile(cur ^ 1, kt + 1);
        MEMFENCE;
        if (have_next) asm volatile("s_waitcnt vmcnt(4) lgkmcnt(0)" ::: "memory");
        else           asm volatile("s_waitcnt vmcnt(0) lgkmcnt(0)" ::: "memory");
        __builtin_amdgcn_s_barrier();
        MEMFENCE;

        const char* kb = smem + cur*8192;
        const char* vb = smem + 16384 + cur*8192;

        // ---- QK: S^T tile, K-dim = 64 feats = 4 ksteps ----
        f32x16 sc;
        #pragma unroll
        for (int r = 0; r < 16; ++r) sc[r] = 0.f;
        {
            const int krow = wk*32 + lq;
            const char* krp = kb + krow*128;
            const int ksw = (krow & 7) << 4;
            #pragma unroll
            for (int ks = 0; ks < 4; ++ks) {
                const short8 ak = *(const short8*)(krp + (((ks*2 + lh) << 4) ^ ksw));
                sc = __builtin_amdgcn_mfma_f32_32x32x16_bf16(ak, qfh[ks], sc, 0, 0, 0);
                sc = __builtin_amdgcn_mfma_f32_32x32x16_bf16(ak, qfl[ks], sc, 0, 0, 0);
            }
        }

        // ---- online softmax (wk-halves independent) ----
        float pm = sc[0];
        #pragma unroll
        for (int r = 1; r < 16; ++r) pm = fmaxf(pm, sc[r]);
        pm *= 0.125f;
        pm = fmaxf(pm, __shfl_xor(pm, 32));
        const float mnew = fmaxf(m_run, pm);
        const float cf   = __expf(m_run - mnew);
        float p[16];
        float ls = 0.f;
        #pragma unroll
        for (int r = 0; r < 16; ++r) {
            p[r] = __expf(sc[r]*0.125f - mnew);
            ls += p[r];
        }
        ls += __shfl_xor(ls, 32);
        l_run = l_run * cf + ls;
        m_run = mnew;
        #pragma unroll
        for (int r = 0; r < 16; ++r) { acc0[r] *= cf; acc1[r] *= cf; }

        // ---- PV: out^T += V^T · P^T ----
        {
            const int vsw = (lq & 7) << 4;
            const char* v0p = vb + lq*128;
            const char* v1p = vb + (lq + 32)*128;
            #pragma unroll
            for (int s = 0; s < 2; ++s) {
                float sh[8];
                #pragma unroll
                for (int j = 0; j < 8; ++j) sh[j] = __shfl_xor(p[8*s + j], 32);
                short8 pf;
                #pragma unroll
                for (int j = 0; j < 8; ++j) {
                    float val;
                    if (lh == 0) val = (j < 4) ? p[8*s + j] : sh[j - 4];
                    else         val = (j < 4) ? sh[4 + j] : p[8*s + j];
                    uint32_t u = __builtin_bit_cast(uint32_t, val);
                    u += 0x7fffu + ((u >> 16) & 1u);
                    pf[j] = (short)(u >> 16);
                }
                const int cb = (wk*4 + s*2 + lh) << 4;
                const short8 a0 = *(const short8*)(v0p + (cb ^ vsw));
                const short8 a1 = *(const short8*)(v1p + (cb ^ vsw));
                acc0 = __builtin_amdgcn_mfma_f32_32x32x16_bf16(a0, pf, acc0, 0, 0, 0);
                acc1 = __builtin_amdgcn_mfma_f32_32x32x16_bf16(a1, pf, acc1, 0, 0, 0);
            }
        }
        MEMFENCE;
        __builtin_amdgcn_s_barrier();
        MEMFENCE;
    }

    // ---- epilogue: merge wk halves (independent m), transpose via LDS ----
    if (lane < 32) { sm_m[wk][wq*32 + lq] = m_run; sm_l[wk][wq*32 + lq] = l_run; }
    __syncthreads();
    const int qrow = wq*32 + lq;
    const float Mq  = fmaxf(sm_m[0][qrow], sm_m[1][qrow]);
    const float wsc = __expf(m_run - Mq);
    if (wk == 0) {
        #pragma unroll
        for (int r = 0; r < 16; ++r) {
            const int dr = (r & 3) + 8*(r >> 2) + 4*lh;
            osum[qrow][dr     ] = acc0[r] * wsc;
            osum[qrow][dr + 32] = acc1[r] * wsc;
        }
    }
    __syncthreads();
    if (wk == 1) {
        #pragma unroll
        for (int r = 0; r < 16; ++r) {
            const int dr = (r & 3) + 8*(r >> 2) + 4*lh;
            osum[qrow][dr     ] += acc0[r] * wsc;
            osum[qrow][dr + 32] += acc1[r] * wsc;
        }
    }
    __syncthreads();
    {
        const int q  = tid >> 2;
        const int d0 = (tid & 3) * 16;
        const float M     = fmaxf(sm_m[0][q], sm_m[1][q]);
        const float lcomb = __expf(sm_m[0][q] - M) * sm_l[0][q]
                          + __expf(sm_m[1][q] - M) * sm_l[1][q];
        if (is_glob) {
            float* WACC = (float*)(ws + OFF_WACC);
            float* WM   = (float*)(ws + OFF_WM);
            float* WL   = (float*)(ws + OFF_WL);
            const int slot = chunk * NBH + bh;
            float* dst = WACC + (size_t)slot * 4096 + q * 64 + d0;
            #pragma unroll
            for (int i = 0; i < 16; i += 4) {
                float4 o;
                o.x = osum[q][d0 + i    ];
                o.y = osum[q][d0 + i + 1];
                o.z = osum[q][d0 + i + 2];
                o.w = osum[q][d0 + i + 3];
                *(float4*)(dst + i) = o;
            }
            if ((tid & 3) == 0) {
                WM[slot * 64 + q] = M;
                WL[slot * 64 + q] = lcomb;
            }
        } else {
            const float inv = 1.f / lcomb;
            float* dst = OUT + bh_off + (size_t)(qtok0 + q) * HD + d0;
            #pragma unroll
            for (int i = 0; i < 16; i += 4) {
                float4 o;
                o.x = osum[q][d0 + i    ] * inv;
                o.y = osum[q][d0 + i + 1] * inv;
                o.z = osum[q][d0 + i + 2] * inv;
                o.w = osum[q][d0 + i + 3] * inv;
                *(float4*)(dst + i) = o;
            }
        }
    }
}

// Combine the NCHUNK flash partials for the 64 global query rows of each (b,h).
__global__ __launch_bounds__(256, 4)
void bb_combine(const char* __restrict__ ws, float* __restrict__ OUT)
{
    const int bh = blockIdx.x;
    const int b  = bh >> 4;
    const int hd = bh & 15;
    const size_t bh_off = ((size_t)b * TT * HH + hd) * DD;

    const float* WACC = (const float*)(ws + OFF_WACC);
    const float* WM   = (const float*)(ws + OFF_WM);
    const float* WL   = (const float*)(ws + OFF_WL);

    const int q  = threadIdx.x >> 2;
    const int d0 = (threadIdx.x & 3) * 16;

    float m[NCHUNK];
    float M = -INFINITY;
    #pragma unroll
    for (int c = 0; c < NCHUNK; ++c) {
        m[c] = WM[(c * NBH + bh) * 64 + q];
        M = fmaxf(M, m[c]);
    }
    float w[NCHUNK];
    float denom = 0.f;
    #pragma unroll
    for (int c = 0; c < NCHUNK; ++c) {
        w[c] = __expf(m[c] - M);
        denom += w[c] * WL[(c * NBH + bh) * 64 + q];
    }
    const float inv = 1.f / denom;

    float* dst = OUT + bh_off + (size_t)q * HD + d0;
    #pragma unroll
    for (int i = 0; i < 16; i += 4) {
        float ox = 0.f, oy = 0.f, oz = 0.f, ow = 0.f;
        #pragma unroll
        for (int c = 0; c < NCHUNK; ++c) {
            const float4 a = *(const float4*)&WACC[(size_t)(c * NBH + bh) * 4096 + q * 64 + d0 + i];
            ox += w[c] * a.x; oy += w[c] * a.y;
            oz += w[c] * a.z; ow += w[c] * a.w;
        }
        float4 o; o.x = ox * inv; o.y = oy * inv; o.z = oz * inv; o.w = ow * inv;
        *(float4*)(dst + i) = o;
    }
}

extern "C" void kernel_launch(void* const* d_in, const int* in_sizes, int n_in,
                              void* d_out, int out_size, void* d_ws, size_t ws_size,
                              hipStream_t stream) {
    const float* Q    = (const float*)d_in[0];
    const float* K    = (const float*)d_in[1];
    const float* V    = (const float*)d_in[2];
    const int*   RIDX = (const int*)d_in[3];
    float* OUT = (float*)d_out;
    char*  ws  = (char*)d_ws;

    // 1) convert K/V to bf16 (+ V^T, gathered random V^T) into workspace
    hipLaunchKernelGGL(bb_prep, dim3(8192 + 1024 + 64), dim3(256), 0, stream,
                       K, V, RIDX, ws);
    // 2) attention: 512 global-chunk blocks + 4032 sparse blocks
    hipLaunchKernelGGL(bb_mfma, dim3(NGBLK + NSPB), dim3(256), 0, stream,
                       Q, RIDX, OUT, ws);
    // 3) combine global partials (writes OUT rows [0,64) per (b,h))
    hipLaunchKernelGGL(bb_combine, dim3(NBH), dim3(256), 0, stream, ws, OUT);
}